// Round 2
// baseline (831.655 us; speedup 1.0000x reference)
//
#include <hip/hip_runtime.h>
#include <hip/hip_bf16.h>
#include <math.h>

#define N_NODES 100000
#define D_IN 256
#define H1 16
#define H2 32

// ============================ common small kernels ============================

__global__ void k_zero(float4* __restrict__ p, int n4) {
    int i = blockIdx.x * blockDim.x + threadIdx.x;
    if (i < n4) p[i] = make_float4(0.f, 0.f, 0.f, 0.f);
}

// ---------------- t = x @ W1  [N,256]@[256,16] ----------------
// One thread per row. x row streamed as float4 (each 64B line consumed over
// consecutive k via L1). W1 accesses are wave-uniform -> scalar s_load through
// the constant cache: zero LDS, zero VALU overhead for weights.
__global__ __launch_bounds__(256) void k_xw1(const float4* __restrict__ x4,
                                             const float* __restrict__ W1,
                                             float* __restrict__ t, int n) {
    int i = blockIdx.x * 256 + threadIdx.x;
    if (i >= n) return;
    float acc[H1];
#pragma unroll
    for (int f = 0; f < H1; f++) acc[f] = 0.f;
    const float4* xr = x4 + (size_t)i * (D_IN / 4);
    for (int kc = 0; kc < D_IN / 4; kc++) {
        float4 xv = xr[kc];
#pragma unroll
        for (int f = 0; f < H1; f++) {
            acc[f] = fmaf(xv.x, W1[(kc * 4 + 0) * H1 + f], acc[f]);
            acc[f] = fmaf(xv.y, W1[(kc * 4 + 1) * H1 + f], acc[f]);
            acc[f] = fmaf(xv.z, W1[(kc * 4 + 2) * H1 + f], acc[f]);
            acc[f] = fmaf(xv.w, W1[(kc * 4 + 3) * H1 + f], acc[f]);
        }
    }
    float4* t4 = (float4*)t;
#pragma unroll
    for (int q = 0; q < 4; q++)
        t4[i * 4 + q] = make_float4(acc[q * 4], acc[q * 4 + 1],
                                    acc[q * 4 + 2], acc[q * 4 + 3]);
}

// ============================ CSR-build pipeline ============================

// deg[r]++ ; colsum[c] += v   (6.4M light atomics, replaces 51.2M fp32 ones)
__global__ __launch_bounds__(256) void k_hist(const int* __restrict__ rows,
                                              const int* __restrict__ cols,
                                              const float* __restrict__ vals,
                                              int* __restrict__ deg,
                                              float* __restrict__ colsum, int E) {
    int e = blockIdx.x * 256 + threadIdx.x;
    if (e >= E) return;
    atomicAdd(&deg[rows[e]], 1);
    atomicAdd(&colsum[cols[e]], vals[e]);
}

// block-local exclusive scan of deg -> rs (no global offset yet); part[b]=total
__global__ __launch_bounds__(1024) void k_scan_a(const int* __restrict__ deg,
                                                 int* __restrict__ rs,
                                                 int* __restrict__ part, int n) {
    __shared__ int sm[1024];
    int tIdx = threadIdx.x;
    int i = blockIdx.x * 1024 + tIdx;
    int v = (i < n) ? deg[i] : 0;
    sm[tIdx] = v;
    __syncthreads();
    for (int off = 1; off < 1024; off <<= 1) {
        int u = (tIdx >= off) ? sm[tIdx - off] : 0;
        __syncthreads();
        if (tIdx >= off) sm[tIdx] += u;
        __syncthreads();
    }
    if (i < n) rs[i] = sm[tIdx] - v;            // exclusive within block
    if (tIdx == 1023) part[blockIdx.x] = sm[tIdx];
}

// serial exclusive scan of the 98 block totals (trivial)
__global__ void k_scan_b(int* __restrict__ part, int nb) {
    if (threadIdx.x == 0 && blockIdx.x == 0) {
        int run = 0;
        for (int j = 0; j < nb; j++) { int p = part[j]; part[j] = run; run += p; }
    }
}

// add block offsets; produce cursor copy; rs[n] = E
__global__ __launch_bounds__(1024) void k_scan_c(int* __restrict__ rs,
                                                 int* __restrict__ cursor,
                                                 const int* __restrict__ part,
                                                 int n, int E) {
    int i = blockIdx.x * 1024 + threadIdx.x;
    if (i < n) {
        int v = rs[i] + part[blockIdx.x];
        rs[i] = v;
        cursor[i] = v;
    }
    if (i == 0) rs[n] = E;
}

// scatter edges into row-grouped payload (col,val packed as float2)
__global__ __launch_bounds__(256) void k_scatter(const int* __restrict__ rows,
                                                 const int* __restrict__ cols,
                                                 const float* __restrict__ vals,
                                                 int* __restrict__ cursor,
                                                 float2* __restrict__ payload, int E) {
    int e = blockIdx.x * 256 + threadIdx.x;
    if (e >= E) return;
    int r = rows[e];
    int pos = atomicAdd(&cursor[r], 1);
    payload[pos] = make_float2(__int_as_float(cols[e]), vals[e]);
}

// gather: one wave per node, lane=(jq,f); zero atomics, acc in registers
__global__ __launch_bounds__(256) void k_gather(const float2* __restrict__ payload,
                                                const int* __restrict__ rs,
                                                const float* __restrict__ t,
                                                float* __restrict__ g, int n) {
    int node = blockIdx.x * 4 + (threadIdx.x >> 6);
    if (node >= n) return;
    int lane = threadIdx.x & 63;
    int f = lane & 15;
    int jq = lane >> 4;                 // 4 edges in flight per wave
    int beg = rs[node], end = rs[node + 1];
    float acc = 0.f;
    for (int j = beg + jq; j < end; j += 4) {
        float2 p = payload[j];
        int c = __float_as_int(p.x);
        acc = fmaf(p.y, t[c * H1 + f], acc);
    }
    acc += __shfl_xor(acc, 16, 64);
    acc += __shfl_xor(acc, 32, 64);
    if (jq == 0) g[node * H1 + f] = acc;
}

// ---------------- s[f] = sum_j colsum[j] * relu(g[j][f]) ----------------
__global__ __launch_bounds__(256) void k_s(const float* __restrict__ g,
                                           const float* __restrict__ colsum,
                                           float* __restrict__ s, int n_nodes) {
    const int f = threadIdx.x & 15;
    int grp = (blockIdx.x * 256 + threadIdx.x) >> 4;
    int ngrp = (gridDim.x * 256) >> 4;
    float acc = 0.f;
    for (int j = grp; j < n_nodes; j += ngrp) {
        float cv = colsum[j];
        float gv = g[j * H1 + f];
        acc = fmaf(cv, fmaxf(gv, 0.f), acc);
    }
    acc += __shfl_xor(acc, 16, 64);
    acc += __shfl_xor(acc, 32, 64);
    __shared__ float red[4][16];
    int lane = threadIdx.x & 63, wid = threadIdx.x >> 6;
    if (lane < 16) red[wid][lane] = acc;
    __syncthreads();
    if (threadIdx.x < 16) {
        float v = red[0][threadIdx.x] + red[1][threadIdx.x] +
                  red[2][threadIdx.x] + red[3][threadIdx.x];
        atomicAdd(&s[threadIdx.x], v);
    }
}

// ---------------- out = sigmoid((s @ W2) @ w_out + b_out) ----------------
__global__ void k_out(const float* __restrict__ s, const float* __restrict__ W2,
                      const float* __restrict__ w_out,
                      const float* __restrict__ b_out, float* __restrict__ out) {
    int f2 = threadIdx.x;
    float m = 0.f;
    if (f2 < H2) {
        float v = 0.f;
#pragma unroll
        for (int f1 = 0; f1 < H1; f1++) v = fmaf(s[f1], W2[f1 * H2 + f2], v);
        m = v * w_out[f2];
    }
    for (int off = 32; off; off >>= 1) m += __shfl_down(m, off, 64);
    if (f2 == 0) out[0] = 1.f / (1.f + expf(-(m + b_out[0])));
}

// ---------------- fallback (old atomic edge pass) if ws too small ----------
__global__ __launch_bounds__(256) void k_edge(const int* __restrict__ rows,
                                              const int* __restrict__ cols,
                                              const float* __restrict__ vals,
                                              const float* __restrict__ t,
                                              float* __restrict__ g,
                                              float* __restrict__ colsum, int E) {
    int tid = blockIdx.x * 256 + threadIdx.x;
    int e = tid >> 4;
    int f = tid & 15;
    if (e >= E) return;
    int r = rows[e];
    int c = cols[e];
    float v = vals[e];
    float tv = t[c * H1 + f];
    atomicAdd(&g[r * H1 + f], v * tv);
    if (f == 0) atomicAdd(&colsum[c], v);
}

extern "C" void kernel_launch(void* const* d_in, const int* in_sizes, int n_in,
                              void* d_out, int out_size, void* d_ws, size_t ws_size,
                              hipStream_t stream) {
    const float* x         = (const float*)d_in[0];
    const float* edge_vals = (const float*)d_in[1];
    const float* W1        = (const float*)d_in[2];
    const float* W2        = (const float*)d_in[3];
    const float* w_out     = (const float*)d_in[4];
    const float* b_out     = (const float*)d_in[5];
    const int*   edge_rows = (const int*)d_in[6];
    const int*   edge_cols = (const int*)d_in[7];
    float* out = (float*)d_out;

    const int N = N_NODES;
    const int E = in_sizes[1];

    char* ws = (char*)d_ws;
    // layout (bytes):
    //   t:       [0,          6,400,000)
    //   g:       [6,400,000, 12,800,000)
    //   payload: [12,800,000, 12.8M+8E)          8E = 25,600,000
    //   deg:     [38,400,000, 38,800,000)  \
    //   colsum:  [38,800,000, 39,200,000)   } contiguous zero region
    //   s:       [39,200,000, 39,200,064)  /
    //   rs:      [39,200,064, 39,600,080)   N+1 ints (padded)
    //   cursor:  [39,600,080, 40,000,080)
    //   part:    [40,000,080, 40,000,592)
    float* t       = (float*)(ws);
    float* g       = (float*)(ws + 6400000);
    float2* payload= (float2*)(ws + 12800000);
    int*   deg     = (int*)  (ws + 38400000);
    float* colsum  = (float*)(ws + 38800000);
    float* s       = (float*)(ws + 39200000);
    int*   rs      = (int*)  (ws + 39200064);
    int*   cursor  = (int*)  (ws + 39600080);
    int*   part    = (int*)  (ws + 40000080);

    const bool big_ws = (ws_size >= 40000592) && (E == 3200000);

    // t = x @ W1 (independent of edge pipeline)
    k_xw1<<<(N + 255) / 256, 256, 0, stream>>>((const float4*)x, W1, t, N);

    if (big_ws) {
        // zero deg+colsum+s: 800,064 B = 50,004 float4
        k_zero<<<(50004 + 255) / 256, 256, 0, stream>>>((float4*)deg, 50004);

        k_hist<<<(E + 255) / 256, 256, 0, stream>>>(edge_rows, edge_cols,
                                                    edge_vals, deg, colsum, E);

        const int nb = (N + 1023) / 1024;   // 98
        k_scan_a<<<nb, 1024, 0, stream>>>(deg, rs, part, N);
        k_scan_b<<<1, 64, 0, stream>>>(part, nb);
        k_scan_c<<<nb, 1024, 0, stream>>>(rs, cursor, part, N, E);

        k_scatter<<<(E + 255) / 256, 256, 0, stream>>>(edge_rows, edge_cols,
                                                       edge_vals, cursor, payload, E);

        k_gather<<<(N + 3) / 4, 256, 0, stream>>>(payload, rs, t, g, N);
    } else {
        // fallback: old atomic path (layout: g, colsum, s as above; zero them)
        k_zero<<<(400000 + 255) / 256, 256, 0, stream>>>((float4*)g, 400000);
        k_zero<<<(25004 + 255) / 256, 256, 0, stream>>>((float4*)colsum, 25004);
        int edge_threads = E * 16;
        k_edge<<<(edge_threads + 255) / 256, 256, 0, stream>>>(
            edge_rows, edge_cols, edge_vals, t, g, colsum, E);
    }

    k_s<<<1024, 256, 0, stream>>>(g, colsum, s, N);

    k_out<<<1, 64, 0, stream>>>(s, W2, w_out, b_out, out);
}

// Round 3
// 753.805 us; speedup vs baseline: 1.1033x; 1.1033x over previous
//
#include <hip/hip_runtime.h>
#include <hip/hip_bf16.h>
#include <math.h>

#define N_NODES 100000
#define D_IN 256
#define H1 16
#define H2 32
#define BSHIFT 7                      // 128 rows per bucket
#define NBUK ((N_NODES + 127) >> 7)   // 782

// ---------------- zero a float region ----------------
__global__ void k_zero(float4* __restrict__ p, int n4) {
    int i = blockIdx.x * blockDim.x + threadIdx.x;
    if (i < n4) p[i] = make_float4(0.f, 0.f, 0.f, 0.f);
}

// ---------------- t = x @ W1  [N,256]@[256,16] ----------------
// One thread per row; W1 indices are wave-uniform -> scalar-cache loads.
__global__ __launch_bounds__(256) void k_xw1(const float4* __restrict__ x4,
                                             const float* __restrict__ W1,
                                             float* __restrict__ t, int n) {
    int i = blockIdx.x * 256 + threadIdx.x;
    if (i >= n) return;
    float acc[H1];
#pragma unroll
    for (int f = 0; f < H1; f++) acc[f] = 0.f;
    const float4* xr = x4 + (size_t)i * (D_IN / 4);
    for (int kc = 0; kc < D_IN / 4; kc++) {
        float4 xv = xr[kc];
#pragma unroll
        for (int f = 0; f < H1; f++) {
            acc[f] = fmaf(xv.x, W1[(kc * 4 + 0) * H1 + f], acc[f]);
            acc[f] = fmaf(xv.y, W1[(kc * 4 + 1) * H1 + f], acc[f]);
            acc[f] = fmaf(xv.z, W1[(kc * 4 + 2) * H1 + f], acc[f]);
            acc[f] = fmaf(xv.w, W1[(kc * 4 + 3) * H1 + f], acc[f]);
        }
    }
    float4* t4 = (float4*)t;
#pragma unroll
    for (int q = 0; q < 4; q++)
        t4[i * 4 + q] = make_float4(acc[q * 4], acc[q * 4 + 1],
                                    acc[q * 4 + 2], acc[q * 4 + 3]);
}

// ---------------- per-block LDS histogram of row & col buckets ----------------
__global__ __launch_bounds__(256) void k_cnt(const int* __restrict__ rows,
                                             const int* __restrict__ cols,
                                             int* __restrict__ cntR,
                                             int* __restrict__ cntC,
                                             int E, int chunk) {
    __shared__ int hR[NBUK], hC[NBUK];
    for (int i = threadIdx.x; i < NBUK; i += 256) { hR[i] = 0; hC[i] = 0; }
    __syncthreads();
    int beg = blockIdx.x * chunk, end = min(beg + chunk, E);
    for (int e = beg + threadIdx.x; e < end; e += 256) {
        atomicAdd(&hR[rows[e] >> BSHIFT], 1);
        atomicAdd(&hC[cols[e] >> BSHIFT], 1);
    }
    __syncthreads();
    for (int i = threadIdx.x; i < NBUK; i += 256) {
        if (hR[i]) atomicAdd(&cntR[i], hR[i]);
        if (hC[i]) atomicAdd(&cntC[i], hC[i]);
    }
}

// ---------------- exclusive scan of 782 bucket counts (grid=2: R then C) -----
__global__ __launch_bounds__(1024) void k_scan(const int* __restrict__ cntR,
                                               const int* __restrict__ cntC,
                                               int* __restrict__ baseR,
                                               int* __restrict__ curR,
                                               int* __restrict__ baseC,
                                               int* __restrict__ curC) {
    const int* cnt = blockIdx.x ? cntC : cntR;
    int* base = blockIdx.x ? baseC : baseR;
    int* cur  = blockIdx.x ? curC  : curR;
    __shared__ int sm[1024];
    int tid = threadIdx.x;
    int v = (tid < NBUK) ? cnt[tid] : 0;
    sm[tid] = v;
    __syncthreads();
    for (int off = 1; off < 1024; off <<= 1) {
        int u = (tid >= off) ? sm[tid - off] : 0;
        __syncthreads();
        if (tid >= off) sm[tid] += u;
        __syncthreads();
    }
    if (tid < NBUK) { int b = sm[tid] - v; base[tid] = b; cur[tid] = b; }
}

// ---------------- scatter edges into bucket-contiguous payload ----------------
// payload[j] = { (keyLocal<<17) | (other & 0x1FFFF), bits(val) }
__global__ __launch_bounds__(256) void k_scatter(const int* __restrict__ keys,
                                                 const int* __restrict__ other,
                                                 const float* __restrict__ vals,
                                                 int* __restrict__ cursor,
                                                 uint2* __restrict__ payload,
                                                 int E, int chunk) {
    __shared__ int hcnt[NBUK];
    __shared__ int hbas[NBUK];
    for (int i = threadIdx.x; i < NBUK; i += 256) hcnt[i] = 0;
    __syncthreads();
    int beg = blockIdx.x * chunk, end = min(beg + chunk, E);
    for (int e = beg + threadIdx.x; e < end; e += 256)
        atomicAdd(&hcnt[keys[e] >> BSHIFT], 1);
    __syncthreads();
    for (int i = threadIdx.x; i < NBUK; i += 256)
        hbas[i] = hcnt[i] ? atomicAdd(&cursor[i], hcnt[i]) : 0;
    __syncthreads();
    for (int e = beg + threadIdx.x; e < end; e += 256) {
        int k = keys[e];
        int b = k >> BSHIFT;
        int pos = atomicAdd(&hbas[b], 1);
        payload[pos] = make_uint2(((unsigned)(k & 127) << 17) |
                                  ((unsigned)other[e] & 0x1FFFFu),
                                  __float_as_uint(vals[e]));
    }
}

// ---------------- per-bucket accumulate g via LDS (no global atomics) --------
__global__ __launch_bounds__(256) void k_acc_row(const uint2* __restrict__ payload,
                                                 const int* __restrict__ baseR,
                                                 const int* __restrict__ cntR,
                                                 const float* __restrict__ t,
                                                 float* __restrict__ g, int n) {
    __shared__ float gl[128 * H1];
    for (int i = threadIdx.x; i < 128 * H1; i += 256) gl[i] = 0.f;
    __syncthreads();
    int b = blockIdx.x;
    int beg = baseR[b], end = beg + cntR[b];
    int f = threadIdx.x & 15;
    for (int j = beg + (threadIdx.x >> 4); j < end; j += 16) {
        uint2 p = payload[j];
        int col = p.x & 0x1FFFF;
        int rl  = p.x >> 17;
        atomicAdd(&gl[rl * H1 + f], __uint_as_float(p.y) * t[col * H1 + f]);
    }
    __syncthreads();
    int r0 = b << BSHIFT;
    for (int i = threadIdx.x; i < 128 * H1 / 4; i += 256) {   // 512 float4
        int r = r0 + (i >> 2);
        if (r < n) ((float4*)g)[(size_t)r * 4 + (i & 3)] = ((float4*)gl)[i];
    }
}

// ---------------- per-bucket accumulate colsum via LDS ----------------
__global__ __launch_bounds__(256) void k_acc_col(const uint2* __restrict__ payload,
                                                 const int* __restrict__ baseC,
                                                 const int* __restrict__ cntC,
                                                 float* __restrict__ colsum, int n) {
    __shared__ float cs[128];
    if (threadIdx.x < 128) cs[threadIdx.x] = 0.f;
    __syncthreads();
    int b = blockIdx.x;
    int beg = baseC[b], end = beg + cntC[b];
    for (int j = beg + threadIdx.x; j < end; j += 256) {
        uint2 p = payload[j];
        atomicAdd(&cs[p.x >> 17], __uint_as_float(p.y));
    }
    __syncthreads();
    int c0 = b << BSHIFT;
    if (threadIdx.x < 128 && c0 + threadIdx.x < n)
        colsum[c0 + threadIdx.x] = cs[threadIdx.x];
}

// ---------------- s[f] = sum_j colsum[j] * relu(g[j][f]) ----------------
__global__ __launch_bounds__(256) void k_s(const float* __restrict__ g,
                                           const float* __restrict__ colsum,
                                           float* __restrict__ s, int n_nodes) {
    const int f = threadIdx.x & 15;
    int grp = (blockIdx.x * 256 + threadIdx.x) >> 4;
    int ngrp = (gridDim.x * 256) >> 4;
    float acc = 0.f;
    for (int j = grp; j < n_nodes; j += ngrp) {
        float cv = colsum[j];
        float gv = g[j * H1 + f];
        acc = fmaf(cv, fmaxf(gv, 0.f), acc);
    }
    acc += __shfl_xor(acc, 16, 64);
    acc += __shfl_xor(acc, 32, 64);
    __shared__ float red[4][16];
    int lane = threadIdx.x & 63, wid = threadIdx.x >> 6;
    if (lane < 16) red[wid][lane] = acc;
    __syncthreads();
    if (threadIdx.x < 16) {
        float v = red[0][threadIdx.x] + red[1][threadIdx.x] +
                  red[2][threadIdx.x] + red[3][threadIdx.x];
        atomicAdd(&s[threadIdx.x], v);
    }
}

// ---------------- out = sigmoid((s @ W2) @ w_out + b_out) ----------------
__global__ void k_out(const float* __restrict__ s, const float* __restrict__ W2,
                      const float* __restrict__ w_out,
                      const float* __restrict__ b_out, float* __restrict__ out) {
    int f2 = threadIdx.x;
    float m = 0.f;
    if (f2 < H2) {
        float v = 0.f;
#pragma unroll
        for (int f1 = 0; f1 < H1; f1++) v = fmaf(s[f1], W2[f1 * H2 + f2], v);
        m = v * w_out[f2];
    }
    for (int off = 32; off; off >>= 1) m += __shfl_down(m, off, 64);
    if (f2 == 0) out[0] = 1.f / (1.f + expf(-(m + b_out[0])));
}

// ---------------- fallback: wave-coalesced atomic edge pass ----------------
__global__ __launch_bounds__(256) void k_edge(const int* __restrict__ rows,
                                              const int* __restrict__ cols,
                                              const float* __restrict__ vals,
                                              const float* __restrict__ t,
                                              float* __restrict__ g,
                                              float* __restrict__ colsum, int E) {
    int tid = blockIdx.x * 256 + threadIdx.x;
    int e = tid >> 4;
    int f = tid & 15;
    if (e >= E) return;
    int r = rows[e];
    int c = cols[e];
    float v = vals[e];
    float tv = t[c * H1 + f];
    atomicAdd(&g[r * H1 + f], v * tv);
    if (f == 0) atomicAdd(&colsum[c], v);
}

extern "C" void kernel_launch(void* const* d_in, const int* in_sizes, int n_in,
                              void* d_out, int out_size, void* d_ws, size_t ws_size,
                              hipStream_t stream) {
    const float* x         = (const float*)d_in[0];
    const float* edge_vals = (const float*)d_in[1];
    const float* W1        = (const float*)d_in[2];
    const float* W2        = (const float*)d_in[3];
    const float* w_out     = (const float*)d_in[4];
    const float* b_out     = (const float*)d_in[5];
    const int*   edge_rows = (const int*)d_in[6];
    const int*   edge_cols = (const int*)d_in[7];
    float* out = (float*)d_out;

    const int N = N_NODES;
    const int E = in_sizes[1];

    char* ws = (char*)d_ws;
    // layout (bytes):
    //   t:       [0,          6,400,000)
    //   g:       [6,400,000, 12,800,000)
    //   payload: [12,800,000, 12.8M + 8E)        (8E = 25,600,000)
    //   colsum:  [38,400,000, 38,800,000)
    //   s:       [38,800,000, 38,800,064)  \
    //   cntR:    [38,800,064, +3132)        |
    //   cntC:    [38,803,196, +3132)        |  zero region
    //   baseR:   [38,806,328, +3132)        |  (18,864 B incl pad)
    //   curR:    [38,809,460, +3132)        |
    //   baseC:   [38,812,592, +3132)        |
    //   curC:    [38,815,724, +3132)       /
    float*  t       = (float*)(ws);
    float*  g       = (float*)(ws + 6400000);
    uint2*  payload = (uint2*)(ws + 12800000);
    float*  colsum  = (float*)(ws + 38400000);
    float*  s       = (float*)(ws + 38800000);
    int*    cntR    = (int*)  (ws + 38800064);
    int*    cntC    = (int*)  (ws + 38803196);
    int*    baseR   = (int*)  (ws + 38806328);
    int*    curR    = (int*)  (ws + 38809460);
    int*    baseC   = (int*)  (ws + 38812592);
    int*    curC    = (int*)  (ws + 38815724);

    const bool big_ws = (ws_size >= 38818864) && (E <= 3200000);

    // t = x @ W1 (independent of edge pipeline)
    k_xw1<<<(N + 255) / 256, 256, 0, stream>>>((const float4*)x, W1, t, N);

    if (big_ws) {
        // zero s + cnt/base/cur region: 18,864 B = 1179 float4
        k_zero<<<(1179 + 255) / 256, 256, 0, stream>>>((float4*)s, 1179);

        const int G = 512;
        const int chunk = (E + G - 1) / G;
        k_cnt<<<G, 256, 0, stream>>>(edge_rows, edge_cols, cntR, cntC, E, chunk);
        k_scan<<<2, 1024, 0, stream>>>(cntR, cntC, baseR, curR, baseC, curC);

        // row-keyed: payload -> g (LDS accumulate, no global atomics)
        k_scatter<<<G, 256, 0, stream>>>(edge_rows, edge_cols, edge_vals,
                                         curR, payload, E, chunk);
        k_acc_row<<<NBUK, 256, 0, stream>>>(payload, baseR, cntR, t, g, N);

        // col-keyed (reuses payload buffer): payload -> colsum
        k_scatter<<<G, 256, 0, stream>>>(edge_cols, edge_rows, edge_vals,
                                         curC, payload, E, chunk);
        k_acc_col<<<NBUK, 256, 0, stream>>>(payload, baseC, cntC, colsum, N);
    } else {
        // fallback: wave-coalesced atomic path
        k_zero<<<(400000 + 255) / 256, 256, 0, stream>>>((float4*)g, 400000);
        k_zero<<<(25004 + 255) / 256, 256, 0, stream>>>((float4*)colsum, 25004);
        int edge_threads = E * 16;
        k_edge<<<(edge_threads + 255) / 256, 256, 0, stream>>>(
            edge_rows, edge_cols, edge_vals, t, g, colsum, E);
    }

    k_s<<<1024, 256, 0, stream>>>(g, colsum, s, N);
    k_out<<<1, 64, 0, stream>>>(s, W2, w_out, b_out, out);
}

// Round 4
// 738.174 us; speedup vs baseline: 1.1266x; 1.0212x over previous
//
#include <hip/hip_runtime.h>
#include <hip/hip_bf16.h>
#include <math.h>

#define N_NODES 100000
#define D_IN 256
#define H1 16
#define H2 32
#define BSHIFT 7                      // 128 rows per bucket
#define NBUK ((N_NODES + 127) >> 7)   // 782

// ---------------- zero a float region ----------------
__global__ void k_zero(float4* __restrict__ p, int n4) {
    int i = blockIdx.x * blockDim.x + threadIdx.x;
    if (i < n4) p[i] = make_float4(0.f, 0.f, 0.f, 0.f);
}

// ---------------- t = x @ W1  [N,256]@[256,16] ----------------
// LDS-staged: 256 rows/block, 8 k-passes of 32 floats (32KB tile). Staging is
// coalesced float4; compute reads own row via XOR-swizzled ds_read_b128
// (8-way conflict, hidden under 2x FMA issue); W1 indices wave-uniform ->
// scalar-cache s_loads. acc[16] in VGPRs.
__global__ __launch_bounds__(256) void k_xw1(const float4* __restrict__ x4,
                                             const float* __restrict__ W1,
                                             float* __restrict__ t, int n) {
    __shared__ float4 xs[2048];   // 32 KB: 256 rows x 8 float4
    float acc[H1];
#pragma unroll
    for (int f = 0; f < H1; f++) acc[f] = 0.f;
    const int rbase = blockIdx.x * 256;
    const int row = rbase + threadIdx.x;
#pragma unroll 1
    for (int pass = 0; pass < 8; pass++) {
        if (pass) __syncthreads();
        for (int idx = threadIdx.x; idx < 2048; idx += 256) {
            int r = idx >> 3, q = idx & 7;
            int gr = rbase + r;
            float4 v = (gr < n) ? x4[(size_t)gr * 64 + pass * 8 + q]
                                : make_float4(0.f, 0.f, 0.f, 0.f);
            xs[r * 8 + (q ^ (r & 7))] = v;
        }
        __syncthreads();
        const int rl = threadIdx.x;
#pragma unroll
        for (int q = 0; q < 8; q++) {
            float4 xv = xs[rl * 8 + (q ^ (rl & 7))];
            int k0 = pass * 32 + q * 4;
#pragma unroll
            for (int f = 0; f < H1; f++) {
                acc[f] = fmaf(xv.x, W1[(k0 + 0) * H1 + f], acc[f]);
                acc[f] = fmaf(xv.y, W1[(k0 + 1) * H1 + f], acc[f]);
                acc[f] = fmaf(xv.z, W1[(k0 + 2) * H1 + f], acc[f]);
                acc[f] = fmaf(xv.w, W1[(k0 + 3) * H1 + f], acc[f]);
            }
        }
    }
    if (row < n) {
        float4* t4 = (float4*)t;
#pragma unroll
        for (int qq = 0; qq < 4; qq++)
            t4[(size_t)row * 4 + qq] = make_float4(acc[qq * 4], acc[qq * 4 + 1],
                                                   acc[qq * 4 + 2], acc[qq * 4 + 3]);
    }
}

// ---------------- per-block LDS histogram of row & col buckets ----------------
__global__ __launch_bounds__(256) void k_cnt(const int* __restrict__ rows,
                                             const int* __restrict__ cols,
                                             int* __restrict__ cntR,
                                             int* __restrict__ cntC,
                                             int E, int chunk) {
    __shared__ int hR[NBUK], hC[NBUK];
    for (int i = threadIdx.x; i < NBUK; i += 256) { hR[i] = 0; hC[i] = 0; }
    __syncthreads();
    int beg = blockIdx.x * chunk, end = min(beg + chunk, E);
    for (int e = beg + threadIdx.x; e < end; e += 256) {
        atomicAdd(&hR[rows[e] >> BSHIFT], 1);
        atomicAdd(&hC[cols[e] >> BSHIFT], 1);
    }
    __syncthreads();
    for (int i = threadIdx.x; i < NBUK; i += 256) {
        if (hR[i]) atomicAdd(&cntR[i], hR[i]);
        if (hC[i]) atomicAdd(&cntC[i], hC[i]);
    }
}

// ---------------- exclusive scan of 782 bucket counts (grid=2: R then C) -----
__global__ __launch_bounds__(1024) void k_scan(const int* __restrict__ cntR,
                                               const int* __restrict__ cntC,
                                               int* __restrict__ baseR,
                                               int* __restrict__ curR,
                                               int* __restrict__ baseC,
                                               int* __restrict__ curC) {
    const int* cnt = blockIdx.x ? cntC : cntR;
    int* base = blockIdx.x ? baseC : baseR;
    int* cur  = blockIdx.x ? curC  : curR;
    __shared__ int sm[1024];
    int tid = threadIdx.x;
    int v = (tid < NBUK) ? cnt[tid] : 0;
    sm[tid] = v;
    __syncthreads();
    for (int off = 1; off < 1024; off <<= 1) {
        int u = (tid >= off) ? sm[tid - off] : 0;
        __syncthreads();
        if (tid >= off) sm[tid] += u;
        __syncthreads();
    }
    if (tid < NBUK) { int b = sm[tid] - v; base[tid] = b; cur[tid] = b; }
}

// ---------------- scatter edges into bucket-contiguous payload ----------------
// payload[j] = { (keyLocal<<17) | (other & 0x1FFFF), bits(val) }
__global__ __launch_bounds__(256) void k_scatter(const int* __restrict__ keys,
                                                 const int* __restrict__ other,
                                                 const float* __restrict__ vals,
                                                 int* __restrict__ cursor,
                                                 uint2* __restrict__ payload,
                                                 int E, int chunk) {
    __shared__ int hcnt[NBUK];
    __shared__ int hbas[NBUK];
    for (int i = threadIdx.x; i < NBUK; i += 256) hcnt[i] = 0;
    __syncthreads();
    int beg = blockIdx.x * chunk, end = min(beg + chunk, E);
    for (int e = beg + threadIdx.x; e < end; e += 256)
        atomicAdd(&hcnt[keys[e] >> BSHIFT], 1);
    __syncthreads();
    for (int i = threadIdx.x; i < NBUK; i += 256)
        hbas[i] = hcnt[i] ? atomicAdd(&cursor[i], hcnt[i]) : 0;
    __syncthreads();
    for (int e = beg + threadIdx.x; e < end; e += 256) {
        int k = keys[e];
        int b = k >> BSHIFT;
        int pos = atomicAdd(&hbas[b], 1);
        payload[pos] = make_uint2(((unsigned)(k & 127) << 17) |
                                  ((unsigned)other[e] & 0x1FFFFu),
                                  __float_as_uint(vals[e]));
    }
}

// ---------------- per-bucket accumulate colsum via LDS ----------------
__global__ __launch_bounds__(1024) void k_acc_col(const uint2* __restrict__ payload,
                                                  const int* __restrict__ baseC,
                                                  const int* __restrict__ cntC,
                                                  float* __restrict__ colsum, int n) {
    __shared__ float cs[128];
    if (threadIdx.x < 128) cs[threadIdx.x] = 0.f;
    __syncthreads();
    int b = blockIdx.x;
    int beg = baseC[b], end = beg + cntC[b];
    for (int j = beg + threadIdx.x; j < end; j += 1024) {
        uint2 p = payload[j];
        atomicAdd(&cs[p.x >> 17], __uint_as_float(p.y));
    }
    __syncthreads();
    int c0 = b << BSHIFT;
    if (threadIdx.x < 128 && c0 + threadIdx.x < n)
        colsum[c0 + threadIdx.x] = cs[threadIdx.x];
}

// ---------------- per-bucket: accumulate g-tile in LDS, fuse the k_s
// reduction into the epilogue (g never hits global memory). ----------------
__global__ __launch_bounds__(1024) void k_acc_row(const uint2* __restrict__ payload,
                                                  const int* __restrict__ baseR,
                                                  const int* __restrict__ cntR,
                                                  const float* __restrict__ t,
                                                  const float* __restrict__ colsum,
                                                  float* __restrict__ s, int n) {
    __shared__ float gl[128 * H1];   // 8 KB
    __shared__ float red[16][16];
    for (int i = threadIdx.x; i < 128 * H1; i += 1024) gl[i] = 0.f;
    __syncthreads();
    const int b = blockIdx.x;
    const int beg = baseR[b], cnt = cntR[b];
    const int f = threadIdx.x & 15;
    const int slot = threadIdx.x >> 4;             // 0..63
    const uint2* pl = payload + beg;
    // contiguous chunk per slot, unroll-4 two-phase for MLP
    const int chunk = (cnt + 63) >> 6;
    const int s0 = min(slot * chunk, cnt);
    const int s1 = min(s0 + chunk, cnt);
    int j = s0;
    for (; j + 4 <= s1; j += 4) {
        uint2 p0 = pl[j], p1 = pl[j + 1], p2 = pl[j + 2], p3 = pl[j + 3];
        float t0 = t[(p0.x & 0x1FFFF) * H1 + f];
        float t1 = t[(p1.x & 0x1FFFF) * H1 + f];
        float t2 = t[(p2.x & 0x1FFFF) * H1 + f];
        float t3 = t[(p3.x & 0x1FFFF) * H1 + f];
        atomicAdd(&gl[(p0.x >> 17) * H1 + f], __uint_as_float(p0.y) * t0);
        atomicAdd(&gl[(p1.x >> 17) * H1 + f], __uint_as_float(p1.y) * t1);
        atomicAdd(&gl[(p2.x >> 17) * H1 + f], __uint_as_float(p2.y) * t2);
        atomicAdd(&gl[(p3.x >> 17) * H1 + f], __uint_as_float(p3.y) * t3);
    }
    for (; j < s1; j++) {
        uint2 p = pl[j];
        atomicAdd(&gl[(p.x >> 17) * H1 + f],
                  __uint_as_float(p.y) * t[(p.x & 0x1FFFF) * H1 + f]);
    }
    __syncthreads();
    // epilogue: s[f] += sum_r colsum[r0+r] * relu(gl[r][f])
    const int r0 = b << BSHIFT;
    float v = 0.f;
#pragma unroll
    for (int h = 0; h < 2; h++) {
        int r = slot + h * 64;
        int gr = r0 + r;
        float cv = (gr < n) ? colsum[gr] : 0.f;
        v = fmaf(cv, fmaxf(gl[r * H1 + f], 0.f), v);
    }
    v += __shfl_xor(v, 16, 64);
    v += __shfl_xor(v, 32, 64);
    int wid = threadIdx.x >> 6, lane = threadIdx.x & 63;
    if (lane < 16) red[wid][lane] = v;
    __syncthreads();
    if (threadIdx.x < 16) {
        float a = 0.f;
#pragma unroll
        for (int w = 0; w < 16; w++) a += red[w][threadIdx.x];
        atomicAdd(&s[threadIdx.x], a);
    }
}

// ---------------- out = sigmoid((s @ W2) @ w_out + b_out) ----------------
__global__ void k_out(const float* __restrict__ s, const float* __restrict__ W2,
                      const float* __restrict__ w_out,
                      const float* __restrict__ b_out, float* __restrict__ out) {
    int f2 = threadIdx.x;
    float m = 0.f;
    if (f2 < H2) {
        float v = 0.f;
#pragma unroll
        for (int f1 = 0; f1 < H1; f1++) v = fmaf(s[f1], W2[f1 * H2 + f2], v);
        m = v * w_out[f2];
    }
    for (int off = 32; off; off >>= 1) m += __shfl_down(m, off, 64);
    if (f2 == 0) out[0] = 1.f / (1.f + expf(-(m + b_out[0])));
}

// ---------------- fallback path (small ws): coalesced atomics ----------------
__global__ __launch_bounds__(256) void k_edge(const int* __restrict__ rows,
                                              const int* __restrict__ cols,
                                              const float* __restrict__ vals,
                                              const float* __restrict__ t,
                                              float* __restrict__ g,
                                              float* __restrict__ colsum, int E) {
    int tid = blockIdx.x * 256 + threadIdx.x;
    int e = tid >> 4;
    int f = tid & 15;
    if (e >= E) return;
    int r = rows[e];
    int c = cols[e];
    float v = vals[e];
    float tv = t[c * H1 + f];
    atomicAdd(&g[r * H1 + f], v * tv);
    if (f == 0) atomicAdd(&colsum[c], v);
}

__global__ __launch_bounds__(256) void k_s(const float* __restrict__ g,
                                           const float* __restrict__ colsum,
                                           float* __restrict__ s, int n_nodes) {
    const int f = threadIdx.x & 15;
    int grp = (blockIdx.x * 256 + threadIdx.x) >> 4;
    int ngrp = (gridDim.x * 256) >> 4;
    float acc = 0.f;
    for (int j = grp; j < n_nodes; j += ngrp) {
        float cv = colsum[j];
        float gv = g[j * H1 + f];
        acc = fmaf(cv, fmaxf(gv, 0.f), acc);
    }
    acc += __shfl_xor(acc, 16, 64);
    acc += __shfl_xor(acc, 32, 64);
    __shared__ float red[4][16];
    int lane = threadIdx.x & 63, wid = threadIdx.x >> 6;
    if (lane < 16) red[wid][lane] = acc;
    __syncthreads();
    if (threadIdx.x < 16) {
        float v = red[0][threadIdx.x] + red[1][threadIdx.x] +
                  red[2][threadIdx.x] + red[3][threadIdx.x];
        atomicAdd(&s[threadIdx.x], v);
    }
}

extern "C" void kernel_launch(void* const* d_in, const int* in_sizes, int n_in,
                              void* d_out, int out_size, void* d_ws, size_t ws_size,
                              hipStream_t stream) {
    const float* x         = (const float*)d_in[0];
    const float* edge_vals = (const float*)d_in[1];
    const float* W1        = (const float*)d_in[2];
    const float* W2        = (const float*)d_in[3];
    const float* w_out     = (const float*)d_in[4];
    const float* b_out     = (const float*)d_in[5];
    const int*   edge_rows = (const int*)d_in[6];
    const int*   edge_cols = (const int*)d_in[7];
    float* out = (float*)d_out;

    const int N = N_NODES;
    const int E = in_sizes[1];

    char* ws = (char*)d_ws;
    // layout (bytes):
    //   t:       [0,          6,400,000)
    //   payload: [6,400,000, 32,000,000)      8E = 25,600,000
    //   colsum:  [32,000,000, 32,400,000)
    //   s:       [32,400,000, 32,400,064)  \
    //   cntR:    [32,400,064, 32,403,264)   } zero region (6,464 B)
    //   cntC:    [32,403,264, 32,406,464)  /
    //   baseR:   [32,406,464, 32,409,664)
    //   curR:    [32,409,664, 32,412,864)
    //   baseC:   [32,412,864, 32,416,064)
    //   curC:    [32,416,064, 32,419,264)
    float*  t       = (float*)(ws);
    uint2*  payload = (uint2*)(ws + 6400000);
    float*  colsum  = (float*)(ws + 32000000);
    float*  s       = (float*)(ws + 32400000);
    int*    cntR    = (int*)  (ws + 32400064);
    int*    cntC    = (int*)  (ws + 32403264);
    int*    baseR   = (int*)  (ws + 32406464);
    int*    curR    = (int*)  (ws + 32409664);
    int*    baseC   = (int*)  (ws + 32412864);
    int*    curC    = (int*)  (ws + 32416064);

    const bool big_ws = (ws_size >= 32419264) && (E <= 3200000);

    // t = x @ W1 (independent of edge pipeline)
    k_xw1<<<(N + 255) / 256, 256, 0, stream>>>((const float4*)x, W1, t, N);

    if (big_ws) {
        // zero s + cntR + cntC: 6,464 B = 404 float4
        k_zero<<<2, 256, 0, stream>>>((float4*)s, 404);

        const int G = 512;
        const int chunk = (E + G - 1) / G;
        k_cnt<<<G, 256, 0, stream>>>(edge_rows, edge_cols, cntR, cntC, E, chunk);
        k_scan<<<2, 1024, 0, stream>>>(cntR, cntC, baseR, curR, baseC, curC);

        // col pipeline first: colsum
        k_scatter<<<G, 256, 0, stream>>>(edge_cols, edge_rows, edge_vals,
                                         curC, payload, E, chunk);
        k_acc_col<<<NBUK, 1024, 0, stream>>>(payload, baseC, cntC, colsum, N);

        // row pipeline (reuses payload); k_s fused into epilogue
        k_scatter<<<G, 256, 0, stream>>>(edge_rows, edge_cols, edge_vals,
                                         curR, payload, E, chunk);
        k_acc_row<<<NBUK, 1024, 0, stream>>>(payload, baseR, cntR, t, colsum, s, N);
    } else {
        // fallback: wave-coalesced atomic path
        // g at ws+6,400,000 (payload region unused), colsum/s as above
        float* g = (float*)(ws + 6400000);
        k_zero<<<(400000 + 255) / 256, 256, 0, stream>>>((float4*)g, 400000);
        k_zero<<<(100016 + 255) / 256, 256, 0, stream>>>((float4*)colsum, 100016 / 4);
        int edge_threads = E * 16;
        k_edge<<<(edge_threads + 255) / 256, 256, 0, stream>>>(
            edge_rows, edge_cols, edge_vals, t, g, colsum, E);
        k_s<<<1024, 256, 0, stream>>>(g, colsum, s, N);
    }

    k_out<<<1, 64, 0, stream>>>(s, W2, w_out, b_out, out);
}

// Round 5
// 713.537 us; speedup vs baseline: 1.1655x; 1.0345x over previous
//
#include <hip/hip_runtime.h>
#include <hip/hip_bf16.h>
#include <math.h>

#define N_NODES 100000
#define D_IN 256
#define H1 16
#define H2 32
#define BSHIFT 7                      // 128 rows per bucket
#define NBUK ((N_NODES + 127) >> 7)   // 782
#define CGSH 13                       // col-group = col >> 13 (8192 cols)
#define NCG 13                        // ceil(100000 / 8192)
#define TILE 4672                     // max bucket size for in-LDS sort (73*64)
#define CRANGE 32768                  // colsum LDS range per block

// ---------------- zero a float region ----------------
__global__ void k_zero(float4* __restrict__ p, int n4) {
    int i = blockIdx.x * blockDim.x + threadIdx.x;
    if (i < n4) p[i] = make_float4(0.f, 0.f, 0.f, 0.f);
}

// ---------------- t = x @ W1  [N,256]@[256,16] ----------------
__global__ __launch_bounds__(256) void k_xw1(const float4* __restrict__ x4,
                                             const float* __restrict__ W1,
                                             float* __restrict__ t, int n) {
    __shared__ float4 xs[2048];   // 32 KB: 256 rows x 8 float4
    float acc[H1];
#pragma unroll
    for (int f = 0; f < H1; f++) acc[f] = 0.f;
    const int rbase = blockIdx.x * 256;
    const int row = rbase + threadIdx.x;
#pragma unroll 1
    for (int pass = 0; pass < 8; pass++) {
        if (pass) __syncthreads();
        for (int idx = threadIdx.x; idx < 2048; idx += 256) {
            int r = idx >> 3, q = idx & 7;
            int gr = rbase + r;
            float4 v = (gr < n) ? x4[(size_t)gr * 64 + pass * 8 + q]
                                : make_float4(0.f, 0.f, 0.f, 0.f);
            xs[r * 8 + (q ^ (r & 7))] = v;
        }
        __syncthreads();
        const int rl = threadIdx.x;
#pragma unroll
        for (int q = 0; q < 8; q++) {
            float4 xv = xs[rl * 8 + (q ^ (rl & 7))];
            int k0 = pass * 32 + q * 4;
#pragma unroll
            for (int f = 0; f < H1; f++) {
                acc[f] = fmaf(xv.x, W1[(k0 + 0) * H1 + f], acc[f]);
                acc[f] = fmaf(xv.y, W1[(k0 + 1) * H1 + f], acc[f]);
                acc[f] = fmaf(xv.z, W1[(k0 + 2) * H1 + f], acc[f]);
                acc[f] = fmaf(xv.w, W1[(k0 + 3) * H1 + f], acc[f]);
            }
        }
    }
    if (row < n) {
        float4* t4 = (float4*)t;
#pragma unroll
        for (int qq = 0; qq < 4; qq++)
            t4[(size_t)row * 4 + qq] = make_float4(acc[qq * 4], acc[qq * 4 + 1],
                                                   acc[qq * 4 + 2], acc[qq * 4 + 3]);
    }
}

// ---------------- colsum (LDS range tiles) + row-bucket histogram ----------
// grid = 4 ranges x 64 chunks. rng==0 blocks also histogram row buckets.
__global__ __launch_bounds__(1024) void k_cnt_colsum(const int* __restrict__ rows,
                                                     const int* __restrict__ cols,
                                                     const float* __restrict__ vals,
                                                     int* __restrict__ cntR,
                                                     float* __restrict__ colsum,
                                                     int E, int n) {
    __shared__ float tile[CRANGE];    // 128 KB
    __shared__ int hR[NBUK];
    const int tid = threadIdx.x;
    const int rng = blockIdx.x >> 6;
    const int chk = blockIdx.x & 63;
    const int base = rng * CRANGE;
    for (int i = tid; i < CRANGE; i += 1024) tile[i] = 0.f;
    const bool do_rows = (rng == 0);
    if (do_rows)
        for (int i = tid; i < NBUK; i += 1024) hR[i] = 0;
    __syncthreads();
    const int cs = (E + 63) >> 6;
    const int e0 = chk * cs, e1 = min(e0 + cs, E);
    for (int e = e0 + tid; e < e1; e += 1024) {
        int c = cols[e];
        unsigned local = (unsigned)(c - base);
        if (local < CRANGE) atomicAdd(&tile[local], vals[e]);
        if (do_rows) atomicAdd(&hR[rows[e] >> BSHIFT], 1);
    }
    __syncthreads();
    for (int i = tid; i < CRANGE; i += 1024) {
        float v = tile[i];
        if (v != 0.f && base + i < n) atomicAdd(&colsum[base + i], v);
    }
    if (do_rows)
        for (int i = tid; i < NBUK; i += 1024) {
            int h = hR[i];
            if (h) atomicAdd(&cntR[i], h);
        }
}

// ---------------- exclusive scan of 782 bucket counts ----------------
__global__ __launch_bounds__(1024) void k_scan(const int* __restrict__ cnt,
                                               int* __restrict__ base,
                                               int* __restrict__ cur) {
    __shared__ int sm[1024];
    int tid = threadIdx.x;
    int v = (tid < NBUK) ? cnt[tid] : 0;
    sm[tid] = v;
    __syncthreads();
    for (int off = 1; off < 1024; off <<= 1) {
        int u = (tid >= off) ? sm[tid - off] : 0;
        __syncthreads();
        if (tid >= off) sm[tid] += u;
        __syncthreads();
    }
    if (tid < NBUK) { int b = sm[tid] - v; base[tid] = b; cur[tid] = b; }
}

// ---------------- scatter edges into row-bucket-contiguous payload ----------
// payload[j] = { (rowLocal<<17) | col, bits(val) }
__global__ __launch_bounds__(256) void k_scatter(const int* __restrict__ keys,
                                                 const int* __restrict__ other,
                                                 const float* __restrict__ vals,
                                                 int* __restrict__ cursor,
                                                 uint2* __restrict__ payload,
                                                 int E, int chunk) {
    __shared__ int hcnt[NBUK];
    __shared__ int hbas[NBUK];
    for (int i = threadIdx.x; i < NBUK; i += 256) hcnt[i] = 0;
    __syncthreads();
    int beg = blockIdx.x * chunk, end = min(beg + chunk, E);
    for (int e = beg + threadIdx.x; e < end; e += 256)
        atomicAdd(&hcnt[keys[e] >> BSHIFT], 1);
    __syncthreads();
    for (int i = threadIdx.x; i < NBUK; i += 256)
        hbas[i] = hcnt[i] ? atomicAdd(&cursor[i], hcnt[i]) : 0;
    __syncthreads();
    for (int e = beg + threadIdx.x; e < end; e += 256) {
        int k = keys[e];
        int b = k >> BSHIFT;
        int pos = atomicAdd(&hbas[b], 1);
        payload[pos] = make_uint2(((unsigned)(k & 127) << 17) |
                                  ((unsigned)other[e] & 0x1FFFFu),
                                  __float_as_uint(vals[e]));
    }
}

// ---------------- per-bucket g-accumulate with in-LDS col-group sort --------
// Sort bucket edges by col-group (13 groups of 8192 cols) so the t-gather
// walks a ~512KB window at a time; all resident blocks stay roughly in
// lockstep -> t window is L2-resident. k_s fused into the epilogue.
__global__ __launch_bounds__(1024) void k_acc_row(const uint2* __restrict__ payload,
                                                  const int* __restrict__ baseR,
                                                  const int* __restrict__ cntR,
                                                  const float* __restrict__ t,
                                                  const float* __restrict__ colsum,
                                                  float* __restrict__ s, int n) {
    __shared__ uint2 tile[TILE];            // 37.4 KB
    __shared__ unsigned short idx16[TILE];  // 9.3 KB
    __shared__ float gl[128 * H1];          // 8 KB
    __shared__ float red[16][16];
    __shared__ int hw[16][NCG];
    __shared__ int btot[NCG], bbase[NCG];

    const int tid = threadIdx.x;
    const int b = blockIdx.x;
    const int beg = baseR[b];
    const int cnt = cntR[b];
    const uint2* pl = payload + beg;

    for (int i = tid; i < 128 * H1; i += 1024) gl[i] = 0.f;
    if (tid < 16 * NCG) ((int*)hw)[tid] = 0;

    const int f = tid & 15;
    const int slot = tid >> 4;    // 0..63
    const int w = tid >> 6;       // wave 0..15
    const int lane = tid & 63;

    if (cnt <= TILE) {
        for (int i = tid; i < cnt; i += 1024) tile[i] = pl[i];
        __syncthreads();
        // phase 1: per-wave 13-bin histogram over this wave's chunk
        const int wc = (cnt + 15) >> 4;
        const int w0 = min(w * wc, cnt), w1 = min(w0 + wc, cnt);
        for (int i = w0 + lane; i < w1; i += 64) {
            int cg = (int)((tile[i].x & 0x1FFFF) >> CGSH);
            atomicAdd(&hw[w][cg], 1);
        }
        __syncthreads();
        // phase 2: hw[w][cg] -> global base for (wave, bin)
        if (tid < NCG) {
            int run = 0;
            for (int ww = 0; ww < 16; ww++) {
                int h = hw[ww][tid];
                hw[ww][tid] = run;
                run += h;
            }
            btot[tid] = run;
        }
        __syncthreads();
        if (tid == 0) {
            int run = 0;
            for (int cg = 0; cg < NCG; cg++) { bbase[cg] = run; run += btot[cg]; }
        }
        __syncthreads();
        if (tid < 16 * NCG) {
            int ww = tid / NCG, cg = tid % NCG;
            hw[ww][cg] += bbase[cg];
        }
        __syncthreads();
        // phase 3: build 16-bit permutation (cg-ascending)
        for (int i = w0 + lane; i < w1; i += 64) {
            int cg = (int)((tile[i].x & 0x1FFFF) >> CGSH);
            int pos = atomicAdd(&hw[w][cg], 1);
            idx16[pos] = (unsigned short)i;
        }
        __syncthreads();
        // process sorted order: 64 consecutive positions per step, unroll 4
        int j = slot;
        for (; j + 192 < cnt; j += 256) {
            int e0 = idx16[j], e1 = idx16[j + 64];
            int e2 = idx16[j + 128], e3 = idx16[j + 192];
            uint2 p0 = tile[e0], p1 = tile[e1], p2 = tile[e2], p3 = tile[e3];
            float t0 = t[(p0.x & 0x1FFFF) * H1 + f];
            float t1 = t[(p1.x & 0x1FFFF) * H1 + f];
            float t2 = t[(p2.x & 0x1FFFF) * H1 + f];
            float t3 = t[(p3.x & 0x1FFFF) * H1 + f];
            atomicAdd(&gl[(p0.x >> 17) * H1 + f], __uint_as_float(p0.y) * t0);
            atomicAdd(&gl[(p1.x >> 17) * H1 + f], __uint_as_float(p1.y) * t1);
            atomicAdd(&gl[(p2.x >> 17) * H1 + f], __uint_as_float(p2.y) * t2);
            atomicAdd(&gl[(p3.x >> 17) * H1 + f], __uint_as_float(p3.y) * t3);
        }
        for (; j < cnt; j += 64) {
            int e = idx16[j];
            uint2 p = tile[e];
            atomicAdd(&gl[(p.x >> 17) * H1 + f],
                      __uint_as_float(p.y) * t[(p.x & 0x1FFFF) * H1 + f]);
        }
    } else {
        // oversized bucket: unsorted direct-from-global (always correct)
        const int chunk = (cnt + 63) >> 6;
        const int s0 = min(slot * chunk, cnt);
        const int s1 = min(s0 + chunk, cnt);
        for (int j = s0; j < s1; j++) {
            uint2 p = pl[j];
            atomicAdd(&gl[(p.x >> 17) * H1 + f],
                      __uint_as_float(p.y) * t[(p.x & 0x1FFFF) * H1 + f]);
        }
    }
    __syncthreads();
    // epilogue: s[f] += sum_r colsum[r0+r] * relu(gl[r][f])
    const int r0 = b << BSHIFT;
    float v = 0.f;
#pragma unroll
    for (int h = 0; h < 2; h++) {
        int r = slot + h * 64;
        int gr = r0 + r;
        float cv = (gr < n) ? colsum[gr] : 0.f;
        v = fmaf(cv, fmaxf(gl[r * H1 + f], 0.f), v);
    }
    v += __shfl_xor(v, 16, 64);
    v += __shfl_xor(v, 32, 64);
    if (lane < 16) red[w][lane] = v;
    __syncthreads();
    if (tid < 16) {
        float a = 0.f;
#pragma unroll
        for (int ww = 0; ww < 16; ww++) a += red[ww][tid];
        atomicAdd(&s[tid], a);
    }
}

// ---------------- out = sigmoid((s @ W2) @ w_out + b_out) ----------------
__global__ void k_out(const float* __restrict__ s, const float* __restrict__ W2,
                      const float* __restrict__ w_out,
                      const float* __restrict__ b_out, float* __restrict__ out) {
    int f2 = threadIdx.x;
    float m = 0.f;
    if (f2 < H2) {
        float v = 0.f;
#pragma unroll
        for (int f1 = 0; f1 < H1; f1++) v = fmaf(s[f1], W2[f1 * H2 + f2], v);
        m = v * w_out[f2];
    }
    for (int off = 32; off; off >>= 1) m += __shfl_down(m, off, 64);
    if (f2 == 0) out[0] = 1.f / (1.f + expf(-(m + b_out[0])));
}

// ---------------- fallback path (small ws): coalesced atomics ----------------
__global__ __launch_bounds__(256) void k_edge(const int* __restrict__ rows,
                                              const int* __restrict__ cols,
                                              const float* __restrict__ vals,
                                              const float* __restrict__ t,
                                              float* __restrict__ g,
                                              float* __restrict__ colsum, int E) {
    int tid = blockIdx.x * 256 + threadIdx.x;
    int e = tid >> 4;
    int f = tid & 15;
    if (e >= E) return;
    int r = rows[e];
    int c = cols[e];
    float v = vals[e];
    float tv = t[c * H1 + f];
    atomicAdd(&g[r * H1 + f], v * tv);
    if (f == 0) atomicAdd(&colsum[c], v);
}

__global__ __launch_bounds__(256) void k_s(const float* __restrict__ g,
                                           const float* __restrict__ colsum,
                                           float* __restrict__ s, int n_nodes) {
    const int f = threadIdx.x & 15;
    int grp = (blockIdx.x * 256 + threadIdx.x) >> 4;
    int ngrp = (gridDim.x * 256) >> 4;
    float acc = 0.f;
    for (int j = grp; j < n_nodes; j += ngrp) {
        float cv = colsum[j];
        float gv = g[j * H1 + f];
        acc = fmaf(cv, fmaxf(gv, 0.f), acc);
    }
    acc += __shfl_xor(acc, 16, 64);
    acc += __shfl_xor(acc, 32, 64);
    __shared__ float red[4][16];
    int lane = threadIdx.x & 63, wid = threadIdx.x >> 6;
    if (lane < 16) red[wid][lane] = acc;
    __syncthreads();
    if (threadIdx.x < 16) {
        float v = red[0][threadIdx.x] + red[1][threadIdx.x] +
                  red[2][threadIdx.x] + red[3][threadIdx.x];
        atomicAdd(&s[threadIdx.x], v);
    }
}

extern "C" void kernel_launch(void* const* d_in, const int* in_sizes, int n_in,
                              void* d_out, int out_size, void* d_ws, size_t ws_size,
                              hipStream_t stream) {
    const float* x         = (const float*)d_in[0];
    const float* edge_vals = (const float*)d_in[1];
    const float* W1        = (const float*)d_in[2];
    const float* W2        = (const float*)d_in[3];
    const float* w_out     = (const float*)d_in[4];
    const float* b_out     = (const float*)d_in[5];
    const int*   edge_rows = (const int*)d_in[6];
    const int*   edge_cols = (const int*)d_in[7];
    float* out = (float*)d_out;

    const int N = N_NODES;
    const int E = in_sizes[1];

    char* ws = (char*)d_ws;
    // layout (bytes):
    //   t:       [0,          6,400,000)
    //   payload: [6,400,000, 32,000,000)      8E = 25,600,000
    //   colsum:  [32,000,000, 32,400,000) \
    //   s:       [32,400,000, 32,400,064)  } contiguous zero region (403,264 B)
    //   cntR:    [32,400,064, 32,403,264) /
    //   baseR:   [32,403,264, 32,406,464)
    //   curR:    [32,406,464, 32,409,664)
    float*  t       = (float*)(ws);
    uint2*  payload = (uint2*)(ws + 6400000);
    float*  colsum  = (float*)(ws + 32000000);
    float*  s       = (float*)(ws + 32400000);
    int*    cntR    = (int*)  (ws + 32400064);
    int*    baseR   = (int*)  (ws + 32403264);
    int*    curR    = (int*)  (ws + 32406464);

    const bool big_ws = (ws_size >= 32409664) && (E <= 3200000);

    k_xw1<<<(N + 255) / 256, 256, 0, stream>>>((const float4*)x, W1, t, N);

    if (big_ws) {
        // zero colsum + s + cntR: 403,264 B = 25,204 float4
        k_zero<<<(25204 + 255) / 256, 256, 0, stream>>>((float4*)colsum, 25204);

        k_cnt_colsum<<<256, 1024, 0, stream>>>(edge_rows, edge_cols, edge_vals,
                                               cntR, colsum, E, N);
        k_scan<<<1, 1024, 0, stream>>>(cntR, baseR, curR);

        const int G = 512;
        const int chunk = (E + G - 1) / G;
        k_scatter<<<G, 256, 0, stream>>>(edge_rows, edge_cols, edge_vals,
                                         curR, payload, E, chunk);
        k_acc_row<<<NBUK, 1024, 0, stream>>>(payload, baseR, cntR, t, colsum, s, N);
    } else {
        // fallback: wave-coalesced atomic path
        float* g = (float*)(ws + 6400000);
        k_zero<<<(400000 + 255) / 256, 256, 0, stream>>>((float4*)g, 400000);
        k_zero<<<(25204 + 255) / 256, 256, 0, stream>>>((float4*)colsum, 25204);
        int edge_threads = E * 16;
        k_edge<<<(edge_threads + 255) / 256, 256, 0, stream>>>(
            edge_rows, edge_cols, edge_vals, t, g, colsum, E);
        k_s<<<1024, 256, 0, stream>>>(g, colsum, s, N);
    }

    k_out<<<1, 64, 0, stream>>>(s, W2, w_out, b_out, out);
}

// Round 6
// 706.795 us; speedup vs baseline: 1.1767x; 1.0095x over previous
//
#include <hip/hip_runtime.h>
#include <hip/hip_bf16.h>
#include <math.h>

#define N_NODES 100000
#define D_IN 256
#define H1 16
#define H2 32
#define BSHIFT 7                      // 128 rows per bucket
#define NBUK ((N_NODES + 127) >> 7)   // 782
#define GLS 17                        // gl row stride (bank-spread padding)
#define CRANGE 32768                  // colsum LDS range per block

// ---------------- zero a float region ----------------
__global__ void k_zero(float4* __restrict__ p, int n4) {
    int i = blockIdx.x * blockDim.x + threadIdx.x;
    if (i < n4) p[i] = make_float4(0.f, 0.f, 0.f, 0.f);
}

// ---------------- t = x @ W1  [N,256]@[256,16] ----------------
__global__ __launch_bounds__(256) void k_xw1(const float4* __restrict__ x4,
                                             const float* __restrict__ W1,
                                             float* __restrict__ t, int n) {
    __shared__ float4 xs[2048];   // 32 KB: 256 rows x 8 float4
    float acc[H1];
#pragma unroll
    for (int f = 0; f < H1; f++) acc[f] = 0.f;
    const int rbase = blockIdx.x * 256;
    const int row = rbase + threadIdx.x;
#pragma unroll 1
    for (int pass = 0; pass < 8; pass++) {
        if (pass) __syncthreads();
        for (int idx = threadIdx.x; idx < 2048; idx += 256) {
            int r = idx >> 3, q = idx & 7;
            int gr = rbase + r;
            float4 v = (gr < n) ? x4[(size_t)gr * 64 + pass * 8 + q]
                                : make_float4(0.f, 0.f, 0.f, 0.f);
            xs[r * 8 + (q ^ (r & 7))] = v;
        }
        __syncthreads();
        const int rl = threadIdx.x;
#pragma unroll
        for (int q = 0; q < 8; q++) {
            float4 xv = xs[rl * 8 + (q ^ (rl & 7))];
            int k0 = pass * 32 + q * 4;
#pragma unroll
            for (int f = 0; f < H1; f++) {
                acc[f] = fmaf(xv.x, W1[(k0 + 0) * H1 + f], acc[f]);
                acc[f] = fmaf(xv.y, W1[(k0 + 1) * H1 + f], acc[f]);
                acc[f] = fmaf(xv.z, W1[(k0 + 2) * H1 + f], acc[f]);
                acc[f] = fmaf(xv.w, W1[(k0 + 3) * H1 + f], acc[f]);
            }
        }
    }
    if (row < n) {
        float4* t4 = (float4*)t;
#pragma unroll
        for (int qq = 0; qq < 4; qq++)
            t4[(size_t)row * 4 + qq] = make_float4(acc[qq * 4], acc[qq * 4 + 1],
                                                   acc[qq * 4 + 2], acc[qq * 4 + 3]);
    }
}

// ---------------- colsum (LDS range tiles) + row-bucket histogram ----------
__global__ __launch_bounds__(1024) void k_cnt_colsum(const int* __restrict__ rows,
                                                     const int* __restrict__ cols,
                                                     const float* __restrict__ vals,
                                                     int* __restrict__ cntR,
                                                     float* __restrict__ colsum,
                                                     int E, int n) {
    __shared__ float tile[CRANGE];    // 128 KB
    __shared__ int hR[NBUK];
    const int tid = threadIdx.x;
    const int rng = blockIdx.x >> 6;
    const int chk = blockIdx.x & 63;
    const int base = rng * CRANGE;
    for (int i = tid; i < CRANGE; i += 1024) tile[i] = 0.f;
    const bool do_rows = (rng == 0);
    if (do_rows)
        for (int i = tid; i < NBUK; i += 1024) hR[i] = 0;
    __syncthreads();
    const int cs = (E + 63) >> 6;
    const int e0 = chk * cs, e1 = min(e0 + cs, E);
    for (int e = e0 + tid; e < e1; e += 1024) {
        int c = cols[e];
        unsigned local = (unsigned)(c - base);
        if (local < CRANGE) atomicAdd(&tile[local], vals[e]);
        if (do_rows) atomicAdd(&hR[rows[e] >> BSHIFT], 1);
    }
    __syncthreads();
    for (int i = tid; i < CRANGE; i += 1024) {
        float v = tile[i];
        if (v != 0.f && base + i < n) atomicAdd(&colsum[base + i], v);
    }
    if (do_rows)
        for (int i = tid; i < NBUK; i += 1024) {
            int h = hR[i];
            if (h) atomicAdd(&cntR[i], h);
        }
}

// ---------------- exclusive scan of 782 bucket counts ----------------
__global__ __launch_bounds__(1024) void k_scan(const int* __restrict__ cnt,
                                               int* __restrict__ base,
                                               int* __restrict__ cur) {
    __shared__ int sm[1024];
    int tid = threadIdx.x;
    int v = (tid < NBUK) ? cnt[tid] : 0;
    sm[tid] = v;
    __syncthreads();
    for (int off = 1; off < 1024; off <<= 1) {
        int u = (tid >= off) ? sm[tid - off] : 0;
        __syncthreads();
        if (tid >= off) sm[tid] += u;
        __syncthreads();
    }
    if (tid < NBUK) { int b = sm[tid] - v; base[tid] = b; cur[tid] = b; }
}

// ---------------- scatter edges into row-bucket-contiguous payload ----------
// payload[j] = { (rowLocal<<17) | col, bits(val) }
__global__ __launch_bounds__(256) void k_scatter(const int* __restrict__ keys,
                                                 const int* __restrict__ other,
                                                 const float* __restrict__ vals,
                                                 int* __restrict__ cursor,
                                                 uint2* __restrict__ payload,
                                                 int E, int chunk) {
    __shared__ int hcnt[NBUK];
    __shared__ int hbas[NBUK];
    for (int i = threadIdx.x; i < NBUK; i += 256) hcnt[i] = 0;
    __syncthreads();
    int beg = blockIdx.x * chunk, end = min(beg + chunk, E);
    for (int e = beg + threadIdx.x; e < end; e += 256)
        atomicAdd(&hcnt[keys[e] >> BSHIFT], 1);
    __syncthreads();
    for (int i = threadIdx.x; i < NBUK; i += 256)
        hbas[i] = hcnt[i] ? atomicAdd(&cursor[i], hcnt[i]) : 0;
    __syncthreads();
    for (int e = beg + threadIdx.x; e < end; e += 256) {
        int k = keys[e];
        int b = k >> BSHIFT;
        int pos = atomicAdd(&hbas[b], 1);
        payload[pos] = make_uint2(((unsigned)(k & 127) << 17) |
                                  ((unsigned)other[e] & 0x1FFFFu),
                                  __float_as_uint(vals[e]));
    }
}

// ---------------- per-bucket g-accumulate: ONE LANE PER EDGE ----------------
// Lane reads payload coalesced (dwordx2), gathers its edge's whole t-row as
// 4 x float4 (4 lane-addresses/edge vs 16 in the lane-per-feature layout),
// then 16 ds_atomic_add_f32 instructions cover 64 edges each. gl stride 17
// spreads rows across banks. k_s reduction fused into the epilogue.
__global__ __launch_bounds__(1024) void k_acc_row(const uint2* __restrict__ payload,
                                                  const int* __restrict__ baseR,
                                                  const int* __restrict__ cntR,
                                                  const float4* __restrict__ t4,
                                                  const float* __restrict__ colsum,
                                                  float* __restrict__ s, int n) {
    __shared__ float gl[128 * GLS];   // 8.7 KB, bank-spread
    __shared__ float red[16][16];
    const int tid = threadIdx.x;
    for (int i = tid; i < 128 * GLS; i += 1024) gl[i] = 0.f;
    __syncthreads();

    const int b = blockIdx.x;
    const int beg = baseR[b];
    const int cnt = cntR[b];
    const uint2* pl = payload + beg;

    int j = tid;
    // unroll 2 for MLP
    for (; j + 1024 < cnt; j += 2048) {
        uint2 p0 = pl[j];
        uint2 p1 = pl[j + 1024];
        unsigned c0 = p0.x & 0x1FFFFu, c1 = p1.x & 0x1FFFFu;
        float v0 = __uint_as_float(p0.y), v1 = __uint_as_float(p1.y);
        const float4* tr0 = t4 + (size_t)c0 * 4;
        const float4* tr1 = t4 + (size_t)c1 * 4;
        float4 a0 = tr0[0], b0 = tr0[1], cc0 = tr0[2], d0 = tr0[3];
        float4 a1 = tr1[0], b1 = tr1[1], cc1 = tr1[2], d1 = tr1[3];
        float* g0 = &gl[(p0.x >> 17) * GLS];
        float* g1 = &gl[(p1.x >> 17) * GLS];
        atomicAdd(g0 + 0, v0 * a0.x);  atomicAdd(g0 + 1, v0 * a0.y);
        atomicAdd(g0 + 2, v0 * a0.z);  atomicAdd(g0 + 3, v0 * a0.w);
        atomicAdd(g0 + 4, v0 * b0.x);  atomicAdd(g0 + 5, v0 * b0.y);
        atomicAdd(g0 + 6, v0 * b0.z);  atomicAdd(g0 + 7, v0 * b0.w);
        atomicAdd(g0 + 8, v0 * cc0.x); atomicAdd(g0 + 9, v0 * cc0.y);
        atomicAdd(g0 + 10, v0 * cc0.z); atomicAdd(g0 + 11, v0 * cc0.w);
        atomicAdd(g0 + 12, v0 * d0.x); atomicAdd(g0 + 13, v0 * d0.y);
        atomicAdd(g0 + 14, v0 * d0.z); atomicAdd(g0 + 15, v0 * d0.w);
        atomicAdd(g1 + 0, v1 * a1.x);  atomicAdd(g1 + 1, v1 * a1.y);
        atomicAdd(g1 + 2, v1 * a1.z);  atomicAdd(g1 + 3, v1 * a1.w);
        atomicAdd(g1 + 4, v1 * b1.x);  atomicAdd(g1 + 5, v1 * b1.y);
        atomicAdd(g1 + 6, v1 * b1.z);  atomicAdd(g1 + 7, v1 * b1.w);
        atomicAdd(g1 + 8, v1 * cc1.x); atomicAdd(g1 + 9, v1 * cc1.y);
        atomicAdd(g1 + 10, v1 * cc1.z); atomicAdd(g1 + 11, v1 * cc1.w);
        atomicAdd(g1 + 12, v1 * d1.x); atomicAdd(g1 + 13, v1 * d1.y);
        atomicAdd(g1 + 14, v1 * d1.z); atomicAdd(g1 + 15, v1 * d1.w);
    }
    for (; j < cnt; j += 1024) {
        uint2 p = pl[j];
        unsigned c = p.x & 0x1FFFFu;
        float v = __uint_as_float(p.y);
        const float4* tr = t4 + (size_t)c * 4;
        float4 a = tr[0], bb = tr[1], cc = tr[2], d = tr[3];
        float* g0 = &gl[(p.x >> 17) * GLS];
        atomicAdd(g0 + 0, v * a.x);  atomicAdd(g0 + 1, v * a.y);
        atomicAdd(g0 + 2, v * a.z);  atomicAdd(g0 + 3, v * a.w);
        atomicAdd(g0 + 4, v * bb.x); atomicAdd(g0 + 5, v * bb.y);
        atomicAdd(g0 + 6, v * bb.z); atomicAdd(g0 + 7, v * bb.w);
        atomicAdd(g0 + 8, v * cc.x); atomicAdd(g0 + 9, v * cc.y);
        atomicAdd(g0 + 10, v * cc.z); atomicAdd(g0 + 11, v * cc.w);
        atomicAdd(g0 + 12, v * d.x); atomicAdd(g0 + 13, v * d.y);
        atomicAdd(g0 + 14, v * d.z); atomicAdd(g0 + 15, v * d.w);
    }
    __syncthreads();

    // epilogue: s[f] += sum_r colsum[r0+r] * relu(gl[r][f])
    const int f = tid & 15;
    const int slot = tid >> 4;    // 0..63
    const int w = tid >> 6;
    const int lane = tid & 63;
    const int r0 = b << BSHIFT;
    float v = 0.f;
#pragma unroll
    for (int h = 0; h < 2; h++) {
        int r = slot + h * 64;
        int gr = r0 + r;
        float cv = (gr < n) ? colsum[gr] : 0.f;
        v = fmaf(cv, fmaxf(gl[r * GLS + f], 0.f), v);
    }
    v += __shfl_xor(v, 16, 64);
    v += __shfl_xor(v, 32, 64);
    if (lane < 16) red[w][lane] = v;
    __syncthreads();
    if (tid < 16) {
        float a = 0.f;
#pragma unroll
        for (int ww = 0; ww < 16; ww++) a += red[ww][tid];
        atomicAdd(&s[tid], a);
    }
}

// ---------------- out = sigmoid((s @ W2) @ w_out + b_out) ----------------
__global__ void k_out(const float* __restrict__ s, const float* __restrict__ W2,
                      const float* __restrict__ w_out,
                      const float* __restrict__ b_out, float* __restrict__ out) {
    int f2 = threadIdx.x;
    float m = 0.f;
    if (f2 < H2) {
        float v = 0.f;
#pragma unroll
        for (int f1 = 0; f1 < H1; f1++) v = fmaf(s[f1], W2[f1 * H2 + f2], v);
        m = v * w_out[f2];
    }
    for (int off = 32; off; off >>= 1) m += __shfl_down(m, off, 64);
    if (f2 == 0) out[0] = 1.f / (1.f + expf(-(m + b_out[0])));
}

// ---------------- fallback path (small ws): coalesced atomics ----------------
__global__ __launch_bounds__(256) void k_edge(const int* __restrict__ rows,
                                              const int* __restrict__ cols,
                                              const float* __restrict__ vals,
                                              const float* __restrict__ t,
                                              float* __restrict__ g,
                                              float* __restrict__ colsum, int E) {
    int tid = blockIdx.x * 256 + threadIdx.x;
    int e = tid >> 4;
    int f = tid & 15;
    if (e >= E) return;
    int r = rows[e];
    int c = cols[e];
    float v = vals[e];
    float tv = t[c * H1 + f];
    atomicAdd(&g[r * H1 + f], v * tv);
    if (f == 0) atomicAdd(&colsum[c], v);
}

__global__ __launch_bounds__(256) void k_s(const float* __restrict__ g,
                                           const float* __restrict__ colsum,
                                           float* __restrict__ s, int n_nodes) {
    const int f = threadIdx.x & 15;
    int grp = (blockIdx.x * 256 + threadIdx.x) >> 4;
    int ngrp = (gridDim.x * 256) >> 4;
    float acc = 0.f;
    for (int j = grp; j < n_nodes; j += ngrp) {
        float cv = colsum[j];
        float gv = g[j * H1 + f];
        acc = fmaf(cv, fmaxf(gv, 0.f), acc);
    }
    acc += __shfl_xor(acc, 16, 64);
    acc += __shfl_xor(acc, 32, 64);
    __shared__ float red[4][16];
    int lane = threadIdx.x & 63, wid = threadIdx.x >> 6;
    if (lane < 16) red[wid][lane] = acc;
    __syncthreads();
    if (threadIdx.x < 16) {
        float v = red[0][threadIdx.x] + red[1][threadIdx.x] +
                  red[2][threadIdx.x] + red[3][threadIdx.x];
        atomicAdd(&s[threadIdx.x], v);
    }
}

extern "C" void kernel_launch(void* const* d_in, const int* in_sizes, int n_in,
                              void* d_out, int out_size, void* d_ws, size_t ws_size,
                              hipStream_t stream) {
    const float* x         = (const float*)d_in[0];
    const float* edge_vals = (const float*)d_in[1];
    const float* W1        = (const float*)d_in[2];
    const float* W2        = (const float*)d_in[3];
    const float* w_out     = (const float*)d_in[4];
    const float* b_out     = (const float*)d_in[5];
    const int*   edge_rows = (const int*)d_in[6];
    const int*   edge_cols = (const int*)d_in[7];
    float* out = (float*)d_out;

    const int N = N_NODES;
    const int E = in_sizes[1];

    char* ws = (char*)d_ws;
    // layout (bytes):
    //   t:       [0,          6,400,000)
    //   payload: [6,400,000, 32,000,000)      8E = 25,600,000
    //   colsum:  [32,000,000, 32,400,000) \
    //   s:       [32,400,000, 32,400,064)  } contiguous zero region (403,264 B)
    //   cntR:    [32,400,064, 32,403,264) /
    //   baseR:   [32,403,264, 32,406,464)
    //   curR:    [32,406,464, 32,409,664)
    float*  t       = (float*)(ws);
    uint2*  payload = (uint2*)(ws + 6400000);
    float*  colsum  = (float*)(ws + 32000000);
    float*  s       = (float*)(ws + 32400000);
    int*    cntR    = (int*)  (ws + 32400064);
    int*    baseR   = (int*)  (ws + 32403264);
    int*    curR    = (int*)  (ws + 32406464);

    const bool big_ws = (ws_size >= 32409664) && (E <= 3200000);

    k_xw1<<<(N + 255) / 256, 256, 0, stream>>>((const float4*)x, W1, t, N);

    if (big_ws) {
        // zero colsum + s + cntR: 403,264 B = 25,204 float4
        k_zero<<<(25204 + 255) / 256, 256, 0, stream>>>((float4*)colsum, 25204);

        k_cnt_colsum<<<256, 1024, 0, stream>>>(edge_rows, edge_cols, edge_vals,
                                               cntR, colsum, E, N);
        k_scan<<<1, 1024, 0, stream>>>(cntR, baseR, curR);

        const int G = 1024;
        const int chunk = (E + G - 1) / G;
        k_scatter<<<G, 256, 0, stream>>>(edge_rows, edge_cols, edge_vals,
                                         curR, payload, E, chunk);
        k_acc_row<<<NBUK, 1024, 0, stream>>>(payload, baseR, cntR,
                                             (const float4*)t, colsum, s, N);
    } else {
        // fallback: wave-coalesced atomic path
        float* g = (float*)(ws + 6400000);
        k_zero<<<(400000 + 255) / 256, 256, 0, stream>>>((float4*)g, 400000);
        k_zero<<<(25204 + 255) / 256, 256, 0, stream>>>((float4*)colsum, 25204);
        int edge_threads = E * 16;
        k_edge<<<(edge_threads + 255) / 256, 256, 0, stream>>>(
            edge_rows, edge_cols, edge_vals, t, g, colsum, E);
        k_s<<<1024, 256, 0, stream>>>(g, colsum, s, N);
    }

    k_out<<<1, 64, 0, stream>>>(s, W2, w_out, b_out, out);
}